// Round 12
// baseline (649.445 us; speedup 1.0000x reference)
//
#include <hip/hip_runtime.h>
#include <stdint.h>

#define HD 64
#define BN_EPS 1e-5f
#define PCH2 8192       // edges per partition block
#define BSH 9           // bucket shift (512 nodes/bucket)  [requires NB <= 512]
#define BSZ 512
#define CAPC 16384      // fixed ebuf capacity per bucket (uint)
#define CAPR 16384      // fixed rbuf capacity per bucket (ushort)
#define ESENT 0xFFFFFFFFu
#define RSENT 0xFFFF

typedef __attribute__((ext_vector_type(8))) short s16x8;
typedef __attribute__((ext_vector_type(4))) float f32x4;
typedef __attribute__((ext_vector_type(2))) float f32x2;

__device__ inline ushort f2bf(float f) {
    union { float f; uint u; } v; v.f = f;
    uint u = v.u + 0x7fffu + ((v.u >> 16) & 1u);
    return (ushort)(u >> 16);
}
__device__ inline float bf2f(ushort b) {
    union { uint u; float f; } v; v.u = ((uint)b) << 16; return v.f;
}
__device__ inline float asf(uint u) {
    union { uint u; float f; } v; v.u = u; return v.f;
}
__device__ inline unsigned char f2f8(float f) {
    uint pk = __builtin_amdgcn_cvt_pk_fp8_f32(f, f, 0, false);
    return (unsigned char)(pk & 0xff);
}

// ---------------- init ----------------

__global__ __launch_bounds__(256)
void k_init(float* __restrict__ cutpad, int* __restrict__ gstart,
            int* __restrict__ bc_col, int* __restrict__ cur_col,
            int* __restrict__ cur_row, int n, int B) {
    int i = blockIdx.x * 256 + threadIdx.x;
    if (i < 2048) cutpad[i] = 0.f;
    if (i <= B + 1) gstart[i] = n;  // sentinel
    if (i < 512) {
        bc_col[i] = 0;
        cur_col[i * 16] = i * CAPC;
        cur_row[i * 16] = i * CAPR;
    }
}

__global__ __launch_bounds__(256)
void k_node_pre(const int* __restrict__ batch, int* __restrict__ gstart, int n) {
    int i = blockIdx.x * 256 + threadIdx.x;
    if (i >= n) return;
    int b = batch[i];
    int bp = (i == 0) ? -1 : batch[i - 1];
    if (b != bp) gstart[b] = i;
}

// partition: LDS-rank edges by bucket, flush full-line-aligned runs with
// sentinel padding. Side-accumulates real per-bucket counts into bc_col.
__global__ __launch_bounds__(256)
void k_partition(const int* __restrict__ row, const int* __restrict__ col,
                 uint* __restrict__ ebuf, ushort* __restrict__ rbuf,
                 int* __restrict__ cur_col, int* __restrict__ cur_row,
                 int* __restrict__ bc_col, int E) {
    __shared__ uint lbuf[PCH2];       // 32 KB
    __shared__ ushort pmap[PCH2];     // 16 KB
    __shared__ int hist[512], lofs[512], gbase[512], gcnt[512];
    __shared__ int sd[256];
    int tid = threadIdx.x;
    int e0 = blockIdx.x * PCH2;
    int cnt_here = E - e0; if (cnt_here > PCH2) cnt_here = PCH2;
    int i0 = tid * 2;

    // ======== phase A: col buckets -> ebuf ========
    hist[tid] = 0; hist[tid + 256] = 0;
    __syncthreads();
    for (int k = 0; k < 32; ++k) {
        int e = e0 + tid + k * 256;
        if (e < E) atomicAdd(&hist[col[e] >> BSH], 1);
    }
    __syncthreads();
    int v0 = hist[i0], v1 = hist[i0 + 1];
    int s2 = v0 + v1;
    sd[tid] = s2;
    __syncthreads();
    for (int o = 1; o < 256; o <<= 1) {
        int t = (tid >= o) ? sd[tid - o] : 0;
        __syncthreads(); sd[tid] += t; __syncthreads();
    }
    int ex = sd[tid] - s2;
    lofs[i0] = ex; lofs[i0 + 1] = ex + v0;
    gcnt[i0] = v0; gcnt[i0 + 1] = v1;
    if (v0) { gbase[i0] = atomicAdd(&cur_col[i0 * 16], (v0 + 15) & ~15);
              atomicAdd(&bc_col[i0], v0); }
    if (v1) { gbase[i0 + 1] = atomicAdd(&cur_col[(i0 + 1) * 16], (v1 + 15) & ~15);
              atomicAdd(&bc_col[i0 + 1], v1); }
    hist[i0] = 0; hist[i0 + 1] = 0;
    __syncthreads();
    for (int k = 0; k < 32; ++k) {
        int e = e0 + tid + k * 256;
        if (e < E) {
            int r = row[e], c = col[e];
            int b = c >> BSH;
            int p = lofs[b] + atomicAdd(&hist[b], 1);
            lbuf[p] = ((uint)r << BSH) | (uint)(c & (BSZ - 1));
            pmap[p] = (ushort)b;
        }
    }
    __syncthreads();
    for (int k = 0; k < 32; ++k) {
        int p = tid + k * 256;
        if (p < cnt_here) {
            int b = pmap[p];
            __builtin_nontemporal_store(lbuf[p], &ebuf[gbase[b] + (p - lofs[b])]);
        }
    }
    // sentinel-pad run tails to full 64B lines
#pragma unroll
    for (int q = 0; q < 2; ++q) {
        int b = i0 + q;
        int v = gcnt[b];
        if (v) {
            int r16 = (v + 15) & ~15;
            for (int p = v; p < r16; ++p)
                __builtin_nontemporal_store(ESENT, &ebuf[gbase[b] + p]);
        }
    }
    __syncthreads();

    // ======== phase B: row buckets -> rbuf (ushort local id) ========
    hist[tid] = 0; hist[tid + 256] = 0;
    __syncthreads();
    for (int k = 0; k < 32; ++k) {
        int e = e0 + tid + k * 256;
        if (e < E) atomicAdd(&hist[row[e] >> BSH], 1);
    }
    __syncthreads();
    v0 = hist[i0]; v1 = hist[i0 + 1];
    s2 = v0 + v1;
    sd[tid] = s2;
    __syncthreads();
    for (int o = 1; o < 256; o <<= 1) {
        int t = (tid >= o) ? sd[tid - o] : 0;
        __syncthreads(); sd[tid] += t; __syncthreads();
    }
    ex = sd[tid] - s2;
    lofs[i0] = ex; lofs[i0 + 1] = ex + v0;
    gcnt[i0] = v0; gcnt[i0 + 1] = v1;
    if (v0) gbase[i0] = atomicAdd(&cur_row[i0 * 16], (v0 + 15) & ~15);
    if (v1) gbase[i0 + 1] = atomicAdd(&cur_row[(i0 + 1) * 16], (v1 + 15) & ~15);
    hist[i0] = 0; hist[i0 + 1] = 0;
    __syncthreads();
    for (int k = 0; k < 32; ++k) {
        int e = e0 + tid + k * 256;
        if (e < E) {
            int r = row[e];
            int b = r >> BSH;
            int p = lofs[b] + atomicAdd(&hist[b], 1);
            lbuf[p] = (uint)r;
            pmap[p] = (ushort)b;
        }
    }
    __syncthreads();
    for (int k = 0; k < 32; ++k) {
        int p = tid + k * 256;
        if (p < cnt_here) {
            int b = pmap[p];
            __builtin_nontemporal_store((ushort)(lbuf[p] & (BSZ - 1)),
                                        &rbuf[gbase[b] + (p - lofs[b])]);
        }
    }
#pragma unroll
    for (int q = 0; q < 2; ++q) {
        int b = i0 + q;
        int v = gcnt[b];
        if (v) {
            int r16 = (v + 15) & ~15;
            for (int p = v; p < r16; ++p)
                __builtin_nontemporal_store((ushort)RSENT, &rbuf[gbase[b] + p]);
        }
    }
}

// one block (after partition): scan real bucket counts -> cbase; gstart suffix-min
__global__ __launch_bounds__(256)
void scan_mid2(const int* __restrict__ bc_col, int* __restrict__ cbase,
               int* __restrict__ gstart, int* __restrict__ rowptr,
               int n, int B, int NB, int E) {
    __shared__ int sd[256];
    int tid = threadIdx.x;
    int i0 = tid * 2;
    int v0 = (i0 < NB) ? bc_col[i0] : 0;
    int v1 = (i0 + 1 < NB) ? bc_col[i0 + 1] : 0;
    int s2 = v0 + v1;
    sd[tid] = s2;
    __syncthreads();
    for (int o = 1; o < 256; o <<= 1) {
        int t = (tid >= o) ? sd[tid - o] : 0;
        __syncthreads(); sd[tid] += t; __syncthreads();
    }
    int ex = sd[tid] - s2;
    if (i0 < NB)     cbase[i0] = ex;
    if (i0 + 1 < NB) cbase[i0 + 1] = ex + v0;
    if (tid == 0) cbase[NB] = E;
    __syncthreads();
    int g = (tid <= B) ? gstart[tid] : 0x7fffffff;
    sd[tid] = g;
    __syncthreads();
    for (int o = 1; o < 256; o <<= 1) {
        int t = (tid + o < 256) ? sd[tid + o] : 0x7fffffff;
        __syncthreads(); sd[tid] = min(sd[tid], t); __syncthreads();
    }
    if (tid <= B) gstart[tid] = sd[tid];
    if (tid == 0) rowptr[n] = E;
}

// per bucket: CSR (count+scan+fill into compact srcs) + out-degree + maskA.
// ebuf/rbuf regions are sentinel-padded; srcs/rowptr remain gap-free.
__global__ __launch_bounds__(256)
void k_bucket_all(const uint* __restrict__ ebuf, const int* __restrict__ cur_col,
                  const ushort* __restrict__ rbuf, const int* __restrict__ cur_row,
                  const int* __restrict__ cbase, const float* __restrict__ x,
                  int* __restrict__ rowptr, float* __restrict__ maskA,
                  int* __restrict__ srcs, float* __restrict__ deg, int n) {
    __shared__ int cnt2[BSZ];
    __shared__ int flg[BSZ];
    __shared__ int ss[256];
    int b = blockIdx.x, tid = threadIdx.x;
    int node0 = b << BSH;
    int e0 = b * CAPC, e1 = cur_col[b * 16];
    cnt2[tid] = 0; cnt2[tid + 256] = 0; flg[tid] = 0; flg[tid + 256] = 0;
    __syncthreads();
    for (int e = e0 + tid; e < e1; e += 256) {
        uint pk = ebuf[e];
        if (pk != ESENT) {
            int lc = pk & (BSZ - 1);
            atomicAdd(&cnt2[lc], 1);
            if (x[pk >> BSH] != 0.f) flg[lc] = 1;  // benign race
        }
    }
    __syncthreads();
    int i0 = tid * 2;
    int v0 = cnt2[i0], v1 = cnt2[i0 + 1];
    int s2 = v0 + v1;
    ss[tid] = s2;
    __syncthreads();
    for (int o = 1; o < 256; o <<= 1) {
        int t = (tid >= o) ? ss[tid - o] : 0;
        __syncthreads(); ss[tid] += t; __syncthreads();
    }
    int ex = ss[tid] - s2;
    cnt2[i0] = ex; cnt2[i0 + 1] = ex + v0;
    __syncthreads();
    int cb = cbase[b];
#pragma unroll
    for (int k = 0; k < 2; ++k) {
        int idx = tid + k * 256;
        int node = node0 + idx;
        if (node < n) {
            rowptr[node] = cb + cnt2[idx];
            float own = (x[node] != 0.f) ? 1.f : 0.f;
            maskA[node] = (own != 0.f || flg[idx]) ? 1.f : 0.f;
        }
    }
    __syncthreads();
    for (int e = e0 + tid; e < e1; e += 256) {
        uint pk = ebuf[e];
        if (pk != ESENT) {
            int lc = pk & (BSZ - 1);
            int pos = atomicAdd(&cnt2[lc], 1);
            srcs[cb + pos] = (int)(pk >> BSH);
        }
    }
    __syncthreads();
    flg[tid] = 0; flg[tid + 256] = 0;
    __syncthreads();
    int r0 = b * CAPR, r1 = cur_row[b * 16];
    for (int e = r0 + tid; e < r1; e += 256) {
        ushort v = rbuf[e];
        if (v != RSENT) atomicAdd(&flg[v], 1);
    }
    __syncthreads();
#pragma unroll
    for (int k = 0; k < 2; ++k) {
        int idx = tid + k * 256;
        int node = node0 + idx;
        if (node < n) deg[node] = (float)flg[idx];
    }
}

// ---------------- gathers ----------------

__global__ __launch_bounds__(256)
void k_gather_s(const float* __restrict__ x, const int* __restrict__ rowptr,
                const int* __restrict__ srcs, float* __restrict__ aggs, int n) {
    int i = blockIdx.x * 256 + threadIdx.x;
    if (i >= n) return;
    float acc = x[i];
    int s = rowptr[i], e = rowptr[i + 1];
    int p = s;
    for (; p + 4 <= e; p += 4) {
        int j0 = srcs[p], j1 = srcs[p + 1], j2 = srcs[p + 2], j3 = srcs[p + 3];
        acc += x[j0] + x[j1] + x[j2] + x[j3];
    }
    for (; p < e; ++p) acc += x[srcs[p]];
    aggs[i] = acc;
}

// fp8 neighbor gather: quarter-wave per node (16 lanes x 4 fp8 ch as uint).
__global__ __launch_bounds__(256)
void gather_f8(const unsigned char* __restrict__ h8, const ushort* __restrict__ hb,
               const int* __restrict__ rowptr, const int* __restrict__ srcs,
               const float* __restrict__ maskA, ushort* __restrict__ outb,
               float* __restrict__ maskB, int n) {
    int tid = threadIdx.x;
    int sub = tid >> 4;
    int ql = tid & 15;
    int node = blockIdx.x * 16 + sub;
    if (node >= n) return;
    const uint2 sv = *(const uint2*)(hb + (long)node * HD + ql * 4);
    float a0 = asf(sv.x << 16);
    float a1 = asf(sv.x & 0xffff0000u);
    float a2 = asf(sv.y << 16);
    float a3 = asf(sv.y & 0xffff0000u);
    float m = maskA[node];
    long co = ql * 4;
    int s = rowptr[node], e = rowptr[node + 1];
    int p = s;
    for (; p + 8 <= e; p += 8) {
        int j0 = srcs[p],     j1 = srcs[p + 1], j2 = srcs[p + 2], j3 = srcs[p + 3];
        int j4 = srcs[p + 4], j5 = srcs[p + 5], j6 = srcs[p + 6], j7 = srcs[p + 7];
        uint v0 = *(const uint*)(h8 + (long)j0 * HD + co);
        uint v1 = *(const uint*)(h8 + (long)j1 * HD + co);
        uint v2 = *(const uint*)(h8 + (long)j2 * HD + co);
        uint v3 = *(const uint*)(h8 + (long)j3 * HD + co);
        uint v4 = *(const uint*)(h8 + (long)j4 * HD + co);
        uint v5 = *(const uint*)(h8 + (long)j5 * HD + co);
        uint v6 = *(const uint*)(h8 + (long)j6 * HD + co);
        uint v7 = *(const uint*)(h8 + (long)j7 * HD + co);
        float m0 = maskA[j0], m1 = maskA[j1], m2 = maskA[j2], m3 = maskA[j3];
        float m4 = maskA[j4], m5 = maskA[j5], m6 = maskA[j6], m7 = maskA[j7];
        f32x2 l0 = __builtin_amdgcn_cvt_pk_f32_fp8(v0, false);
        f32x2 h0 = __builtin_amdgcn_cvt_pk_f32_fp8(v0, true);
        f32x2 l1 = __builtin_amdgcn_cvt_pk_f32_fp8(v1, false);
        f32x2 h1 = __builtin_amdgcn_cvt_pk_f32_fp8(v1, true);
        f32x2 l2 = __builtin_amdgcn_cvt_pk_f32_fp8(v2, false);
        f32x2 h2 = __builtin_amdgcn_cvt_pk_f32_fp8(v2, true);
        f32x2 l3 = __builtin_amdgcn_cvt_pk_f32_fp8(v3, false);
        f32x2 h3 = __builtin_amdgcn_cvt_pk_f32_fp8(v3, true);
        f32x2 l4 = __builtin_amdgcn_cvt_pk_f32_fp8(v4, false);
        f32x2 h4 = __builtin_amdgcn_cvt_pk_f32_fp8(v4, true);
        f32x2 l5 = __builtin_amdgcn_cvt_pk_f32_fp8(v5, false);
        f32x2 h5 = __builtin_amdgcn_cvt_pk_f32_fp8(v5, true);
        f32x2 l6 = __builtin_amdgcn_cvt_pk_f32_fp8(v6, false);
        f32x2 h6 = __builtin_amdgcn_cvt_pk_f32_fp8(v6, true);
        f32x2 l7 = __builtin_amdgcn_cvt_pk_f32_fp8(v7, false);
        f32x2 h7 = __builtin_amdgcn_cvt_pk_f32_fp8(v7, true);
        a0 += ((l0.x + l1.x) + (l2.x + l3.x)) + ((l4.x + l5.x) + (l6.x + l7.x));
        a1 += ((l0.y + l1.y) + (l2.y + l3.y)) + ((l4.y + l5.y) + (l6.y + l7.y));
        a2 += ((h0.x + h1.x) + (h2.x + h3.x)) + ((h4.x + h5.x) + (h6.x + h7.x));
        a3 += ((h0.y + h1.y) + (h2.y + h3.y)) + ((h4.y + h5.y) + (h6.y + h7.y));
        m += ((m0 + m1) + (m2 + m3)) + ((m4 + m5) + (m6 + m7));
    }
    for (; p < e; ++p) {
        int j = srcs[p];
        uint v = *(const uint*)(h8 + (long)j * HD + co);
        f32x2 lo = __builtin_amdgcn_cvt_pk_f32_fp8(v, false);
        f32x2 hi = __builtin_amdgcn_cvt_pk_f32_fp8(v, true);
        a0 += lo.x; a1 += lo.y; a2 += hi.x; a3 += hi.y;
        m += maskA[j];
    }
    uint o0 = ((uint)f2bf(a1) << 16) | (uint)f2bf(a0);
    uint o1 = ((uint)f2bf(a3) << 16) | (uint)f2bf(a2);
    *(uint2*)(outb + (long)node * HD + ql * 4) = make_uint2(o0, o1);
    if (ql == 0) maskB[node] = (m > 0.f) ? 1.f : 0.f;
}

// ---------------- MFMA dense kernels ----------------

template <int MODE>
__global__ __launch_bounds__(256)
void gin_mfma(const float* __restrict__ agg, const ushort* __restrict__ aggb,
              const float* __restrict__ w1f, const float* __restrict__ W1,
              const float* __restrict__ b1, const float* __restrict__ W2,
              const float* __restrict__ b2, const float* __restrict__ bn1,
              const float* __restrict__ mask, const float* __restrict__ bn2p,
              ushort* __restrict__ hbout, unsigned char* __restrict__ h8, int n) {
    __shared__ ushort wt1[4096];
    __shared__ ushort wt2[4096];
    __shared__ ushort z1[4096];
    int tid = threadIdx.x;
    int l = tid & 63;
    int w = __builtin_amdgcn_readfirstlane(tid >> 6);
    int row0 = blockIdx.x * 64;
    int rbase = row0 + w * 16;
    int lrow = l & 15, lgrp = l >> 4;

#pragma unroll
    for (int i = 0; i < 16; ++i) {
        int e = i * 256 + tid;
        int k = e >> 6, c = e & 63;
        int idx = (c * 64 + k) ^ ((c & 7) << 3);
        if (MODE == 1) wt1[idx] = f2bf(W1[e]);
        wt2[idx] = f2bf(W2[e]);
    }
    __syncthreads();

    int zb = w * 1024;
    if (MODE == 0) {
        float w1v = w1f[l], b1v = b1[l];
#pragma unroll
        for (int i = 0; i < 16; ++i) {
            int grow = rbase + i; if (grow > n - 1) grow = n - 1;
            float a = agg[grow];
            float v = fmaxf(a * w1v + b1v, 0.f);
            z1[zb + ((i * 64 + l) ^ ((i & 7) << 3))] = f2bf(v);
        }
    } else {
        int arow = rbase + lrow; if (arow > n - 1) arow = n - 1;
        s16x8 a0 = *(const s16x8*)(aggb + arow * HD + lgrp * 8);
        s16x8 a1 = *(const s16x8*)(aggb + arow * HD + 32 + lgrp * 8);
#pragma unroll
        for (int ct = 0; ct < 4; ++ct) {
            int c = ct * 16 + lrow;
            s16x8 bb0 = *(const s16x8*)&wt1[(c * 64 + lgrp * 8) ^ ((c & 7) << 3)];
            s16x8 bb1 = *(const s16x8*)&wt1[(c * 64 + 32 + lgrp * 8) ^ ((c & 7) << 3)];
            f32x4 acc = {0.f, 0.f, 0.f, 0.f};
            acc = __builtin_amdgcn_mfma_f32_16x16x32_bf16(a0, bb0, acc, 0, 0, 0);
            acc = __builtin_amdgcn_mfma_f32_16x16x32_bf16(a1, bb1, acc, 0, 0, 0);
            float bv1 = b1[c];
#pragma unroll
            for (int r = 0; r < 4; ++r) {
                int rl = lgrp * 4 + r;
                float v = fmaxf(acc[r] + bv1, 0.f);
                z1[zb + ((rl * 64 + c) ^ ((rl & 7) << 3))] = f2bf(v);
            }
        }
    }
    s16x8 a0 = *(const s16x8*)&z1[zb + ((lrow * 64 + lgrp * 8) ^ ((lrow & 7) << 3))];
    s16x8 a1 = *(const s16x8*)&z1[zb + ((lrow * 64 + 32 + lgrp * 8) ^ ((lrow & 7) << 3))];

    float mk[4];
#pragma unroll
    for (int r = 0; r < 4; ++r) {
        int grow = rbase + lgrp * 4 + r; if (grow > n - 1) grow = n - 1;
        mk[r] = mask[grow];
    }

#pragma unroll
    for (int ct = 0; ct < 4; ++ct) {
        int c = ct * 16 + lrow;
        s16x8 bb0 = *(const s16x8*)&wt2[(c * 64 + lgrp * 8) ^ ((c & 7) << 3)];
        s16x8 bb1 = *(const s16x8*)&wt2[(c * 64 + 32 + lgrp * 8) ^ ((c & 7) << 3)];
        f32x4 acc = {0.f, 0.f, 0.f, 0.f};
        acc = __builtin_amdgcn_mfma_f32_16x16x32_bf16(a0, bb0, acc, 0, 0, 0);
        acc = __builtin_amdgcn_mfma_f32_16x16x32_bf16(a1, bb1, acc, 0, 0, 0);
        float g = bn1[c], be = bn1[64 + c], mn = bn1[128 + c], var = bn1[192 + c];
        float A1 = g / sqrtf(var + BN_EPS), C1 = be - mn * A1;
        float A2 = 1.f, C2 = 0.f;
        if (MODE == 1) {
            float g2 = bn2p[c], be2 = bn2p[64 + c], mn2 = bn2p[128 + c], var2 = bn2p[192 + c];
            A2 = g2 / sqrtf(var2 + BN_EPS); C2 = be2 - mn2 * A2;
        }
        float bv2 = b2[c];
#pragma unroll
        for (int r = 0; r < 4; ++r) {
            int rl = lgrp * 4 + r;
            int grow = rbase + rl;
            if (grow < n) {
                int gi = grow * HD + c;
                float v = fmaxf(acc[r] + bv2, 0.f) * A1 + C1;
                if (MODE == 1) v += bf2f(hbout[gi]);   // residual (in place)
                v *= mk[r];
                if (MODE == 1) v = v * A2 + C2;
                hbout[gi] = f2bf(v);
                h8[gi] = f2f8(v);
            }
        }
    }
}

// head: t = bn2(leaky(X@l1w+b1)*mask); hs = leaky(t@l2w+l2b)*mask
__global__ __launch_bounds__(256)
void head_mfma(const ushort* __restrict__ hb, const float* __restrict__ W1,
               const float* __restrict__ b1, const float* __restrict__ mask,
               const float* __restrict__ bn2p, const float* __restrict__ l2w,
               const float* __restrict__ l2b, float* __restrict__ hs, int n) {
    __shared__ ushort wt1[4096];
    int tid = threadIdx.x;
    int l = tid & 63;
    int w = __builtin_amdgcn_readfirstlane(tid >> 6);
    int row0 = blockIdx.x * 64;
    int rbase = row0 + w * 16;
    int lrow = l & 15, lgrp = l >> 4;

#pragma unroll
    for (int i = 0; i < 16; ++i) {
        int e = i * 256 + tid;
        int k = e >> 6, c = e & 63;
        wt1[(c * 64 + k) ^ ((c & 7) << 3)] = f2bf(W1[e]);
    }
    __syncthreads();

    int arow = rbase + lrow; if (arow > n - 1) arow = n - 1;
    s16x8 a0 = *(const s16x8*)(hb + arow * HD + lgrp * 8);
    s16x8 a1 = *(const s16x8*)(hb + arow * HD + 32 + lgrp * 8);

    float mk[4];
#pragma unroll
    for (int r = 0; r < 4; ++r) {
        int grow = rbase + lgrp * 4 + r; if (grow > n - 1) grow = n - 1;
        mk[r] = mask[grow];
    }

    float part[4] = {0.f, 0.f, 0.f, 0.f};
#pragma unroll
    for (int ct = 0; ct < 4; ++ct) {
        int c = ct * 16 + lrow;
        s16x8 bb0 = *(const s16x8*)&wt1[(c * 64 + lgrp * 8) ^ ((c & 7) << 3)];
        s16x8 bb1 = *(const s16x8*)&wt1[(c * 64 + 32 + lgrp * 8) ^ ((c & 7) << 3)];
        f32x4 acc = {0.f, 0.f, 0.f, 0.f};
        acc = __builtin_amdgcn_mfma_f32_16x16x32_bf16(a0, bb0, acc, 0, 0, 0);
        acc = __builtin_amdgcn_mfma_f32_16x16x32_bf16(a1, bb1, acc, 0, 0, 0);
        float g = bn2p[c], be = bn2p[64 + c], mn = bn2p[128 + c], var = bn2p[192 + c];
        float A2 = g / sqrtf(var + BN_EPS), C2 = be - mn * A2;
        float bv = b1[c];
        float w2v = l2w[c];
#pragma unroll
        for (int r = 0; r < 4; ++r) {
            float v = acc[r] + bv;
            v = (v > 0.f) ? v : 0.01f * v;
            v *= mk[r];
            v = v * A2 + C2;
            part[r] += v * w2v;
        }
    }
    float l2b0 = l2b[0];
#pragma unroll
    for (int r = 0; r < 4; ++r) {
        float p = part[r];
        p += __shfl_xor(p, 1, 64);
        p += __shfl_xor(p, 2, 64);
        p += __shfl_xor(p, 4, 64);
        p += __shfl_xor(p, 8, 64);
        int grow = rbase + lgrp * 4 + r;
        if (lrow == 0 && grow < n) {
            float z = p + l2b0;
            z = (z > 0.f) ? z : 0.01f * z;
            hs[grow] = z * mk[r];
        }
    }
}

// ---------------- per-graph stats ----------------

__global__ __launch_bounds__(256)
void graph_stats(const float* __restrict__ hs, const float* __restrict__ deg,
                 const int* __restrict__ gstart, const float* __restrict__ recf,
                 const float* __restrict__ totv, const float* __restrict__ trand,
                 float* __restrict__ gmax, float* __restrict__ gmin,
                 float* __restrict__ gtar) {
    __shared__ float smx[256], smn[256], ssm[256];
    int b = blockIdx.x, tid = threadIdx.x;
    int s = gstart[b], e = gstart[b + 1];
    float mx = -INFINITY, mn = INFINITY, sm = 0.f;
    for (int i = s + tid; i < e; i += 256) {
        float v = hs[i];
        mx = fmaxf(mx, v); mn = fminf(mn, v); sm += deg[i];
    }
    smx[tid] = mx; smn[tid] = mn; ssm[tid] = sm;
    __syncthreads();
    for (int o = 128; o > 0; o >>= 1) {
        if (tid < o) {
            smx[tid] = fmaxf(smx[tid], smx[tid + o]);
            smn[tid] = fminf(smn[tid], smn[tid + o]);
            ssm[tid] += ssm[tid + o];
        }
        __syncthreads();
    }
    if (tid == 0) {
        gmax[b] = smx[0];
        gmin[b] = smn[0];
        float tv = ssm[0] + 1e-6f;
        float feas = recf[b] / totv[b];
        gtar[b] = (trand[b] * feas * 0.85f + 0.1f) * tv;
    }
}

// ---------------- 30-iteration scan (with fused min-max norm) ----------------

__global__ __launch_bounds__(256)
void scan_iters(float* __restrict__ hs, const float* __restrict__ deg,
                const float* __restrict__ mask, const float* __restrict__ x,
                const int* __restrict__ gstart, const float* __restrict__ gmax,
                const float* __restrict__ gmin, const float* __restrict__ gtar,
                float* __restrict__ ga) {
    __shared__ float w1[4], w2[4];
    __shared__ float a_sh;
    int b = blockIdx.x, tid = threadIdx.x;
    int lane = tid & 63, wid = tid >> 6;
    int s = gstart[b], e = gstart[b + 1];
    float target = gtar[b];
    float gmn = gmin[b], gmx = gmax[b];
    float inv = 1.f / ((gmx + 1e-6f) - gmn);
    int cnt = e - s;
    float a = 1.f;

    if (cnt <= 2048) {
        float hv[8], dm[8], hdm[8];
        float Sdm = 0.f;
#pragma unroll
        for (int k = 0; k < 8; ++k) {
            int i = s + tid + k * 256;
            float h_ = 0.f, d_ = 0.f, m_ = 0.f;
            if (i < e) {
                float raw = hs[i]; d_ = deg[i]; m_ = mask[i];
                h_ = (raw - gmn) * inv;
                h_ = h_ * m_ + m_ * 1e-6f + x[i];
                hs[i] = h_;
            }
            hv[k] = h_;
            float t = d_ * m_;
            dm[k] = t;
            hdm[k] = h_ * t;
            Sdm += t;
        }
        {
            float v = Sdm;
#pragma unroll
            for (int o = 32; o > 0; o >>= 1) v += __shfl_down(v, o, 64);
            if (lane == 0) w1[wid] = v;
            __syncthreads();
            if (tid == 0) a_sh = w1[0] + w1[1] + w1[2] + w1[3];
            __syncthreads();
            Sdm = a_sh;
            __syncthreads();
        }
        for (int it = 0; it < 30; ++it) {
            float t1 = 0.f, t2 = 0.f;
#pragma unroll
            for (int k = 0; k < 8; ++k) {
                float keep = (a * hv[k] < 1.f) ? 1.f : 0.f;
                t1 += dm[k] * keep;
                t2 += hdm[k] * keep;
            }
#pragma unroll
            for (int o = 32; o > 0; o >>= 1) {
                t1 += __shfl_down(t1, o, 64);
                t2 += __shfl_down(t2, o, 64);
            }
            if (lane == 0) { w1[wid] = t1; w2[wid] = t2; }
            __syncthreads();
            if (tid == 0) {
                float dnk = Sdm - (w1[0] + w1[1] + w1[2] + w1[3]);
                float dot = w2[0] + w2[1] + w2[2] + w2[3];
                a_sh = (target - dnk) / (dot + 1e-5f);
            }
            __syncthreads();
            a = a_sh;
        }
    } else {
        __shared__ float s1[256], s2[256];
        for (int i = s + tid; i < e; i += 256) {
            float raw = hs[i], m_ = mask[i];
            float h_ = (raw - gmn) * inv;
            hs[i] = h_ * m_ + m_ * 1e-6f + x[i];
        }
        __syncthreads();
        for (int it = 0; it < 30; ++it) {
            float dnk = 0.f, dot = 0.f;
            for (int i = s + tid; i < e; i += 256) {
                float hv = hs[i], d = deg[i], m = mask[i];
                float keep = (a * hv < 1.f) ? 1.f : 0.f;
                float km = keep * m;
                dnk += d * (m - km);
                dot += hv * d * km;
            }
            s1[tid] = dnk; s2[tid] = dot;
            __syncthreads();
            for (int o = 128; o > 0; o >>= 1) {
                if (tid < o) { s1[tid] += s1[tid + o]; s2[tid] += s2[tid + o]; }
                __syncthreads();
            }
            if (tid == 0) a_sh = (target - s1[0]) / (s2[0] + 1e-5f);
            __syncthreads();
            a = a_sh;
        }
    }
    if (tid == 0) ga[b] = a;
}

// ---------------- probs + cut ----------------

__global__ __launch_bounds__(256)
void k_probs(const float* __restrict__ hs, const float* __restrict__ mask,
             const float* __restrict__ deg, const int* __restrict__ batch,
             const float* __restrict__ ga, float* __restrict__ out,
             float* __restrict__ cutpad, int n) {
    int i = blockIdx.x * 256 + threadIdx.x;
    bool valid = i < n;
    int b = valid ? batch[i] : 0;
    float contrib = 0.f;
    if (valid) {
        float p = ga[b] * hs[i] * mask[i];
        p = fminf(fmaxf(p, 0.f), 1.f);
        out[i] = p;
        contrib = p * deg[i];
    }
    int b0 = __shfl(b, 0, 64);
    bool uni = __all(b == b0);
    if (uni) {
#pragma unroll
        for (int o = 32; o > 0; o >>= 1) contrib += __shfl_down(contrib, o, 64);
        if ((threadIdx.x & 63) == 0) atomicAdd(&cutpad[b0 * 16], contrib);
    } else if (valid) {
        atomicAdd(&cutpad[b * 16], contrib);
    }
}

__global__ __launch_bounds__(256)
void cut_edges(const int* __restrict__ row, const int* __restrict__ col,
               const int* __restrict__ batch, const float* __restrict__ probs,
               float* __restrict__ cutpad, int E) {
    __shared__ float lc[128];
    int tid = threadIdx.x;
    if (tid < 128) lc[tid] = 0.f;
    __syncthreads();
    for (int e = blockIdx.x * 256 + tid; e < E; e += gridDim.x * 256) {
        int r = row[e], c = col[e];
        float v = probs[r] * probs[c];
        atomicAdd(&lc[batch[r]], v);
    }
    __syncthreads();
    if (tid < 128) {
        float v = lc[tid];
        if (v != 0.f) atomicAdd(&cutpad[tid * 16], -v);
    }
}

__global__ void k_loss(const float* __restrict__ cutpad, float* __restrict__ out, int nidx, int B) {
    __shared__ float sd[128];
    int tid = threadIdx.x;
    sd[tid] = (tid < B) ? cutpad[tid * 16] : 0.f;
    __syncthreads();
    for (int o = 64; o > 0; o >>= 1) {
        if (tid < o) sd[tid] += sd[tid + o];
        __syncthreads();
    }
    if (tid == 0) out[nidx] = sd[0] / (float)B;
}

// ---------------- host ----------------

extern "C" void kernel_launch(void* const* d_in, const int* in_sizes, int n_in,
                              void* d_out, int out_size, void* d_ws, size_t ws_size,
                              hipStream_t stream) {
    const float* x     = (const float*)d_in[0];
    const int*   ei    = (const int*)d_in[1];
    const int*   batch = (const int*)d_in[2];
    const float* recf  = (const float*)d_in[3];
    const float* totv  = (const float*)d_in[4];
    const float* trand = (const float*)d_in[5];
    const float* c1w1  = (const float*)d_in[6];
    const float* c1b1  = (const float*)d_in[7];
    const float* c1w2  = (const float*)d_in[8];
    const float* c1b2  = (const float*)d_in[9];
    const float* c1bn  = (const float*)d_in[10];
    const float* cw1   = (const float*)d_in[11];
    const float* cb1   = (const float*)d_in[12];
    const float* cw2   = (const float*)d_in[13];
    const float* cb2   = (const float*)d_in[14];
    const float* cbn   = (const float*)d_in[15];
    const float* obn   = (const float*)d_in[16];
    const float* l1w   = (const float*)d_in[17];
    const float* l1b   = (const float*)d_in[18];
    const float* bn2   = (const float*)d_in[19];
    const float* l2w   = (const float*)d_in[20];
    const float* l2b   = (const float*)d_in[21];

    int N  = in_sizes[0];
    int E  = in_sizes[1] / 2;
    int B  = in_sizes[3];
    int NL = in_sizes[11] / (HD * HD);
    const int* row = ei;
    const int* col = ei + E;
    int NB = (N + BSZ - 1) >> BSH;

    long NH = (long)N * HD;
    ushort* hb   = (ushort*)d_ws;            // bf16 [N][64]
    ushort* aggb = hb + NH;                  // bf16 [N][64]
    unsigned char* h8 = (unsigned char*)(aggb + NH);  // fp8 [N][64]
    float* maskA = (float*)(h8 + NH);
    float* maskB = maskA + N;
    float* deg   = maskB + N;
    float* hs    = deg + N;
    float* cutpad = hs + N;
    float* gmax  = cutpad + 2048;
    float* gmin  = gmax + B;
    float* gtar  = gmin + B;
    float* ga    = gtar + B;
    uintptr_t ip = (uintptr_t)(ga + B);
    ip = (ip + 63) & ~(uintptr_t)63;
    int* rowptr  = (int*)ip;
    int* gstart  = rowptr + N + 1;
    int* bc_col  = gstart + (B + 2);
    int* cbase   = bc_col + 512;
    int* cur_col = cbase + 513;              // padded x16
    int* cur_row = cur_col + 512 * 16;       // padded x16
    int* srcs    = cur_row + 512 * 16;
    uintptr_t ip2 = (uintptr_t)(srcs + E);
    ip2 = (ip2 + 63) & ~(uintptr_t)63;
    uint* ebuf   = (uint*)ip2;               // NB*CAPC uints
    ushort* rbuf = (ushort*)(ebuf + (long)NB * CAPC);  // NB*CAPR ushorts

    dim3 blk(256);
    int gN  = (N + 255) / 256;
    int gMM = (N + 63) / 64;
    int g16 = (N + 15) / 16;
    int gP  = (E + PCH2 - 1) / PCH2;

    // ---- preprocessing ----
    k_init<<<gN, blk, 0, stream>>>(cutpad, gstart, bc_col, cur_col, cur_row, N, B);
    k_node_pre<<<gN, blk, 0, stream>>>(batch, gstart, N);
    k_partition<<<gP, blk, 0, stream>>>(row, col, ebuf, rbuf, cur_col, cur_row, bc_col, E);
    scan_mid2<<<1, blk, 0, stream>>>(bc_col, cbase, gstart, rowptr, N, B, NB, E);
    k_bucket_all<<<NB, blk, 0, stream>>>(ebuf, cur_col, rbuf, cur_row, cbase, x,
                                         rowptr, maskA, srcs, deg, N);

    // ---- layer 0 ----
    k_gather_s<<<gN, blk, 0, stream>>>(x, rowptr, srcs, hs, N);
    gin_mfma<0><<<gMM, blk, 0, stream>>>(hs, nullptr, c1w1, nullptr, c1b1,
                                         c1w2, c1b2, c1bn, maskA, nullptr, hb, h8, N);

    // ---- GIN loop ----
    for (int i = 0; i < NL; ++i) {
        gather_f8<<<g16, blk, 0, stream>>>(h8, hb, rowptr, srcs, maskA, aggb, maskB, N);
        gin_mfma<1><<<gMM, blk, 0, stream>>>(nullptr, aggb, nullptr, cw1 + i * 4096,
                                             cb1 + i * 64, cw2 + i * 4096, cb2 + i * 64,
                                             cbn + i * 256, maskB, obn + i * 256, hb, h8, N);
        float* t = maskA; maskA = maskB; maskB = t;
    }

    // ---- head + tail ----
    head_mfma<<<gMM, blk, 0, stream>>>(hb, l1w, l1b, maskA, bn2, l2w, l2b, hs, N);
    graph_stats<<<B, blk, 0, stream>>>(hs, deg, gstart, recf, totv, trand, gmax, gmin, gtar);
    scan_iters<<<B, blk, 0, stream>>>(hs, deg, maskA, x, gstart, gmax, gmin, gtar, ga);
    k_probs<<<gN, blk, 0, stream>>>(hs, maskA, deg, batch, ga, (float*)d_out, cutpad, N);
    cut_edges<<<512, blk, 0, stream>>>(row, col, batch, (float*)d_out, cutpad, E);
    k_loss<<<1, 128, 0, stream>>>(cutpad, (float*)d_out, N, B);
}

// Round 13
// 577.680 us; speedup vs baseline: 1.1242x; 1.1242x over previous
//
#include <hip/hip_runtime.h>
#include <stdint.h>

#define HD 64
#define BN_EPS 1e-5f
#define PCH2 8192       // edges per partition block (16-edge runs = full 64B lines)
#define BSH 9           // bucket shift (512 nodes/bucket)  [requires NB <= 512]
#define BSZ 512

typedef __attribute__((ext_vector_type(8))) short s16x8;
typedef __attribute__((ext_vector_type(4))) float f32x4;
typedef __attribute__((ext_vector_type(2))) float f32x2;

__device__ inline ushort f2bf(float f) {
    union { float f; uint u; } v; v.f = f;
    uint u = v.u + 0x7fffu + ((v.u >> 16) & 1u);
    return (ushort)(u >> 16);
}
__device__ inline float bf2f(ushort b) {
    union { uint u; float f; } v; v.u = ((uint)b) << 16; return v.f;
}
__device__ inline float asf(uint u) {
    union { uint u; float f; } v; v.u = u; return v.f;
}
__device__ inline unsigned char f2f8(float f) {
    uint pk = __builtin_amdgcn_cvt_pk_fp8_f32(f, f, 0, false);
    return (unsigned char)(pk & 0xff);
}

// ---------------- init (+ graph-start boundary detection) ----------------

__global__ __launch_bounds__(256)
void k_init(float* __restrict__ cutpad, int* __restrict__ gstart,
            int* __restrict__ bc_col, int* __restrict__ bc_row,
            const int* __restrict__ batch, int n, int B) {
    int i = blockIdx.x * 256 + threadIdx.x;
    if (i < 2048) cutpad[i] = 0.f;
    if (i < 512) { bc_col[i] = 0; bc_row[i] = 0; }
    if (i < n) {
        int b = batch[i];
        int bp = (i == 0) ? -1 : batch[i - 1];
        if (b != bp) gstart[b] = i;          // boundaries (sorted batch)
        if (i == 0) gstart[B] = n;           // top sentinel
    }
    // unseen graphs fixed by suffix-min in scan_mid (gstart pre-set below)
    if (i <= B + 1 && i > 0) { /* gstart init below via memset-style */ }
}

__global__ __launch_bounds__(256)
void k_gstart_pre(int* __restrict__ gstart, int n, int B) {
    int i = blockIdx.x * 256 + threadIdx.x;
    if (i <= B + 1) gstart[i] = n;
}

// bucket histograms (col and row), LDS-staged
__global__ __launch_bounds__(256)
void k_hist(const int* __restrict__ row, const int* __restrict__ col,
            int* __restrict__ bc_col, int* __restrict__ bc_row, int E) {
    __shared__ int hc[512], hr[512];
    int tid = threadIdx.x;
    hc[tid] = 0; hc[tid + 256] = 0; hr[tid] = 0; hr[tid + 256] = 0;
    __syncthreads();
    int stride = gridDim.x * 256;
    for (int e = blockIdx.x * 256 + tid; e < E; e += stride) {
        atomicAdd(&hc[col[e] >> BSH], 1);
        atomicAdd(&hr[row[e] >> BSH], 1);
    }
    __syncthreads();
#pragma unroll
    for (int k = 0; k < 2; ++k) {
        int i = tid + k * 256;
        if (hc[i]) atomicAdd(&bc_col[i], hc[i]);
        if (hr[i]) atomicAdd(&bc_row[i], hr[i]);
    }
}

// one block: bucket scans, gstart suffix-min, rowptr[n]. Cursors padded x16.
__global__ __launch_bounds__(256)
void scan_mid(const int* __restrict__ bc_col, const int* __restrict__ bc_row,
              int* __restrict__ cbase, int* __restrict__ rbase,
              int* __restrict__ cur_col, int* __restrict__ cur_row,
              int* __restrict__ gstart, int* __restrict__ rowptr,
              int n, int B, int NB, int E) {
    __shared__ int sd[256];
    int tid = threadIdx.x;
    int i0 = tid * 2;
    int v0 = (i0 < NB) ? bc_col[i0] : 0;
    int v1 = (i0 + 1 < NB) ? bc_col[i0 + 1] : 0;
    int s2 = v0 + v1;
    sd[tid] = s2;
    __syncthreads();
    for (int o = 1; o < 256; o <<= 1) {
        int t = (tid >= o) ? sd[tid - o] : 0;
        __syncthreads(); sd[tid] += t; __syncthreads();
    }
    int ex = sd[tid] - s2;
    if (i0 < NB)     { cbase[i0] = ex;          cur_col[i0 * 16] = ex; }
    if (i0 + 1 < NB) { cbase[i0 + 1] = ex + v0; cur_col[(i0 + 1) * 16] = ex + v0; }
    if (tid == 0) cbase[NB] = E;
    __syncthreads();
    v0 = (i0 < NB) ? bc_row[i0] : 0;
    v1 = (i0 + 1 < NB) ? bc_row[i0 + 1] : 0;
    s2 = v0 + v1;
    sd[tid] = s2;
    __syncthreads();
    for (int o = 1; o < 256; o <<= 1) {
        int t = (tid >= o) ? sd[tid - o] : 0;
        __syncthreads(); sd[tid] += t; __syncthreads();
    }
    ex = sd[tid] - s2;
    if (i0 < NB)     { rbase[i0] = ex;          cur_row[i0 * 16] = ex; }
    if (i0 + 1 < NB) { rbase[i0 + 1] = ex + v0; cur_row[(i0 + 1) * 16] = ex + v0; }
    if (tid == 0) rbase[NB] = E;
    __syncthreads();
    int g = (tid <= B) ? gstart[tid] : 0x7fffffff;
    sd[tid] = g;
    __syncthreads();
    for (int o = 1; o < 256; o <<= 1) {
        int t = (tid + o < 256) ? sd[tid + o] : 0x7fffffff;
        __syncthreads(); sd[tid] = min(sd[tid], t); __syncthreads();
    }
    if (tid <= B) gstart[tid] = sd[tid];
    if (tid == 0) rowptr[n] = E;
}

// partition: LDS-rank edges by bucket, flush bucket-contiguous full-line runs.
// pmap written inline during ranking; rbuf stores ushort local row id.
__global__ __launch_bounds__(256)
void k_partition(const int* __restrict__ row, const int* __restrict__ col,
                 uint* __restrict__ ebuf, ushort* __restrict__ rbuf,
                 int* __restrict__ cur_col, int* __restrict__ cur_row, int E) {
    __shared__ uint lbuf[PCH2];       // 32 KB
    __shared__ ushort pmap[PCH2];     // 16 KB: position -> bucket
    __shared__ int hist[512], lofs[512], gbase[512];
    __shared__ int sd[256];
    int tid = threadIdx.x;
    int e0 = blockIdx.x * PCH2;
    int cnt_here = E - e0; if (cnt_here > PCH2) cnt_here = PCH2;
    int i0 = tid * 2;

    // ======== phase A: col buckets -> ebuf ========
    hist[tid] = 0; hist[tid + 256] = 0;
    __syncthreads();
    for (int k = 0; k < 32; ++k) {
        int e = e0 + tid + k * 256;
        if (e < E) atomicAdd(&hist[col[e] >> BSH], 1);
    }
    __syncthreads();
    int v0 = hist[i0], v1 = hist[i0 + 1];
    int s2 = v0 + v1;
    sd[tid] = s2;
    __syncthreads();
    for (int o = 1; o < 256; o <<= 1) {
        int t = (tid >= o) ? sd[tid - o] : 0;
        __syncthreads(); sd[tid] += t; __syncthreads();
    }
    int ex = sd[tid] - s2;
    lofs[i0] = ex; lofs[i0 + 1] = ex + v0;
    if (v0) gbase[i0] = atomicAdd(&cur_col[i0 * 16], v0);
    if (v1) gbase[i0 + 1] = atomicAdd(&cur_col[(i0 + 1) * 16], v1);
    hist[i0] = 0; hist[i0 + 1] = 0;
    __syncthreads();
    for (int k = 0; k < 32; ++k) {
        int e = e0 + tid + k * 256;
        if (e < E) {
            int r = row[e], c = col[e];
            int b = c >> BSH;
            int p = lofs[b] + atomicAdd(&hist[b], 1);
            lbuf[p] = ((uint)r << BSH) | (uint)(c & (BSZ - 1));
            pmap[p] = (ushort)b;
        }
    }
    __syncthreads();
    for (int k = 0; k < 32; ++k) {
        int p = tid + k * 256;
        if (p < cnt_here) {
            int b = pmap[p];
            __builtin_nontemporal_store(lbuf[p], &ebuf[gbase[b] + (p - lofs[b])]);
        }
    }
    __syncthreads();

    // ======== phase B: row buckets -> rbuf (ushort local id) ========
    hist[tid] = 0; hist[tid + 256] = 0;
    __syncthreads();
    for (int k = 0; k < 32; ++k) {
        int e = e0 + tid + k * 256;
        if (e < E) atomicAdd(&hist[row[e] >> BSH], 1);
    }
    __syncthreads();
    v0 = hist[i0]; v1 = hist[i0 + 1];
    s2 = v0 + v1;
    sd[tid] = s2;
    __syncthreads();
    for (int o = 1; o < 256; o <<= 1) {
        int t = (tid >= o) ? sd[tid - o] : 0;
        __syncthreads(); sd[tid] += t; __syncthreads();
    }
    ex = sd[tid] - s2;
    lofs[i0] = ex; lofs[i0 + 1] = ex + v0;
    if (v0) gbase[i0] = atomicAdd(&cur_row[i0 * 16], v0);
    if (v1) gbase[i0 + 1] = atomicAdd(&cur_row[(i0 + 1) * 16], v1);
    hist[i0] = 0; hist[i0 + 1] = 0;
    __syncthreads();
    for (int k = 0; k < 32; ++k) {
        int e = e0 + tid + k * 256;
        if (e < E) {
            int r = row[e];
            int b = r >> BSH;
            int p = lofs[b] + atomicAdd(&hist[b], 1);
            lbuf[p] = (uint)r;
            pmap[p] = (ushort)b;
        }
    }
    __syncthreads();
    for (int k = 0; k < 32; ++k) {
        int p = tid + k * 256;
        if (p < cnt_here) {
            int b = pmap[p];
            __builtin_nontemporal_store((ushort)(lbuf[p] & (BSZ - 1)),
                                        &rbuf[gbase[b] + (p - lofs[b])]);
        }
    }
}

// per bucket: CSR (count+scan+fill) AND out-degree AND maskA — all LDS-local
__global__ __launch_bounds__(256)
void k_bucket_all(const uint* __restrict__ ebuf, const int* __restrict__ cbase,
                  const ushort* __restrict__ rbuf, const int* __restrict__ rbase,
                  const float* __restrict__ x, int* __restrict__ rowptr,
                  float* __restrict__ maskA, int* __restrict__ srcs,
                  float* __restrict__ deg, int n) {
    __shared__ int cnt2[BSZ];
    __shared__ int flg[BSZ];
    __shared__ int ss[256];
    int b = blockIdx.x, tid = threadIdx.x;
    int node0 = b << BSH;
    int e0 = cbase[b], e1 = cbase[b + 1];
    cnt2[tid] = 0; cnt2[tid + 256] = 0; flg[tid] = 0; flg[tid + 256] = 0;
    __syncthreads();
    for (int e = e0 + tid; e < e1; e += 256) {
        uint pk = ebuf[e];
        int lc = pk & (BSZ - 1);
        int r = pk >> BSH;
        atomicAdd(&cnt2[lc], 1);
        if (x[r] != 0.f) flg[lc] = 1;  // benign race
    }
    __syncthreads();
    int i0 = tid * 2;
    int v0 = cnt2[i0], v1 = cnt2[i0 + 1];
    int s2 = v0 + v1;
    ss[tid] = s2;
    __syncthreads();
    for (int o = 1; o < 256; o <<= 1) {
        int t = (tid >= o) ? ss[tid - o] : 0;
        __syncthreads(); ss[tid] += t; __syncthreads();
    }
    int ex = ss[tid] - s2;
    cnt2[i0] = ex; cnt2[i0 + 1] = ex + v0;
    __syncthreads();
#pragma unroll
    for (int k = 0; k < 2; ++k) {
        int idx = tid + k * 256;
        int node = node0 + idx;
        if (node < n) {
            rowptr[node] = e0 + cnt2[idx];
            float own = (x[node] != 0.f) ? 1.f : 0.f;
            maskA[node] = (own != 0.f || flg[idx]) ? 1.f : 0.f;
        }
    }
    __syncthreads();
    for (int e = e0 + tid; e < e1; e += 256) {
        uint pk = ebuf[e];
        int lc = pk & (BSZ - 1);
        int pos = atomicAdd(&cnt2[lc], 1);
        srcs[e0 + pos] = (int)(pk >> BSH);
    }
    __syncthreads();
    flg[tid] = 0; flg[tid + 256] = 0;
    __syncthreads();
    int r0 = rbase[b], r1 = rbase[b + 1];
    for (int e = r0 + tid; e < r1; e += 256)
        atomicAdd(&flg[rbuf[e]], 1);
    __syncthreads();
#pragma unroll
    for (int k = 0; k < 2; ++k) {
        int idx = tid + k * 256;
        int node = node0 + idx;
        if (node < n) deg[node] = (float)flg[idx];
    }
}

// ---------------- gathers ----------------

__global__ __launch_bounds__(256)
void k_gather_s(const float* __restrict__ x, const int* __restrict__ rowptr,
                const int* __restrict__ srcs, float* __restrict__ aggs, int n) {
    int i = blockIdx.x * 256 + threadIdx.x;
    if (i >= n) return;
    float acc = x[i];
    int s = rowptr[i], e = rowptr[i + 1];
    int p = s;
    for (; p + 4 <= e; p += 4) {
        int j0 = srcs[p], j1 = srcs[p + 1], j2 = srcs[p + 2], j3 = srcs[p + 3];
        acc += x[j0] + x[j1] + x[j2] + x[j3];
    }
    for (; p < e; ++p) acc += x[srcs[p]];
    aggs[i] = acc;
}

// fp8 neighbor gather: quarter-wave per node (16 lanes x 4 fp8 ch as uint).
// One 64B cache line per neighbor row; self read from bf16 hb; + mask OR.
__global__ __launch_bounds__(256)
void gather_f8(const unsigned char* __restrict__ h8, const ushort* __restrict__ hb,
               const int* __restrict__ rowptr, const int* __restrict__ srcs,
               const float* __restrict__ maskA, ushort* __restrict__ outb,
               float* __restrict__ maskB, int n) {
    int tid = threadIdx.x;
    int sub = tid >> 4;
    int ql = tid & 15;
    int node = blockIdx.x * 16 + sub;
    if (node >= n) return;
    const uint2 sv = *(const uint2*)(hb + (long)node * HD + ql * 4);
    float a0 = asf(sv.x << 16);
    float a1 = asf(sv.x & 0xffff0000u);
    float a2 = asf(sv.y << 16);
    float a3 = asf(sv.y & 0xffff0000u);
    float m = maskA[node];
    long co = ql * 4;
    int s = rowptr[node], e = rowptr[node + 1];
    int p = s;
    for (; p + 8 <= e; p += 8) {
        int j0 = srcs[p],     j1 = srcs[p + 1], j2 = srcs[p + 2], j3 = srcs[p + 3];
        int j4 = srcs[p + 4], j5 = srcs[p + 5], j6 = srcs[p + 6], j7 = srcs[p + 7];
        uint v0 = *(const uint*)(h8 + (long)j0 * HD + co);
        uint v1 = *(const uint*)(h8 + (long)j1 * HD + co);
        uint v2 = *(const uint*)(h8 + (long)j2 * HD + co);
        uint v3 = *(const uint*)(h8 + (long)j3 * HD + co);
        uint v4 = *(const uint*)(h8 + (long)j4 * HD + co);
        uint v5 = *(const uint*)(h8 + (long)j5 * HD + co);
        uint v6 = *(const uint*)(h8 + (long)j6 * HD + co);
        uint v7 = *(const uint*)(h8 + (long)j7 * HD + co);
        float m0 = maskA[j0], m1 = maskA[j1], m2 = maskA[j2], m3 = maskA[j3];
        float m4 = maskA[j4], m5 = maskA[j5], m6 = maskA[j6], m7 = maskA[j7];
        f32x2 l0 = __builtin_amdgcn_cvt_pk_f32_fp8(v0, false);
        f32x2 h0 = __builtin_amdgcn_cvt_pk_f32_fp8(v0, true);
        f32x2 l1 = __builtin_amdgcn_cvt_pk_f32_fp8(v1, false);
        f32x2 h1 = __builtin_amdgcn_cvt_pk_f32_fp8(v1, true);
        f32x2 l2 = __builtin_amdgcn_cvt_pk_f32_fp8(v2, false);
        f32x2 h2 = __builtin_amdgcn_cvt_pk_f32_fp8(v2, true);
        f32x2 l3 = __builtin_amdgcn_cvt_pk_f32_fp8(v3, false);
        f32x2 h3 = __builtin_amdgcn_cvt_pk_f32_fp8(v3, true);
        f32x2 l4 = __builtin_amdgcn_cvt_pk_f32_fp8(v4, false);
        f32x2 h4 = __builtin_amdgcn_cvt_pk_f32_fp8(v4, true);
        f32x2 l5 = __builtin_amdgcn_cvt_pk_f32_fp8(v5, false);
        f32x2 h5 = __builtin_amdgcn_cvt_pk_f32_fp8(v5, true);
        f32x2 l6 = __builtin_amdgcn_cvt_pk_f32_fp8(v6, false);
        f32x2 h6 = __builtin_amdgcn_cvt_pk_f32_fp8(v6, true);
        f32x2 l7 = __builtin_amdgcn_cvt_pk_f32_fp8(v7, false);
        f32x2 h7 = __builtin_amdgcn_cvt_pk_f32_fp8(v7, true);
        a0 += ((l0.x + l1.x) + (l2.x + l3.x)) + ((l4.x + l5.x) + (l6.x + l7.x));
        a1 += ((l0.y + l1.y) + (l2.y + l3.y)) + ((l4.y + l5.y) + (l6.y + l7.y));
        a2 += ((h0.x + h1.x) + (h2.x + h3.x)) + ((h4.x + h5.x) + (h6.x + h7.x));
        a3 += ((h0.y + h1.y) + (h2.y + h3.y)) + ((h4.y + h5.y) + (h6.y + h7.y));
        m += ((m0 + m1) + (m2 + m3)) + ((m4 + m5) + (m6 + m7));
    }
    for (; p < e; ++p) {
        int j = srcs[p];
        uint v = *(const uint*)(h8 + (long)j * HD + co);
        f32x2 lo = __builtin_amdgcn_cvt_pk_f32_fp8(v, false);
        f32x2 hi = __builtin_amdgcn_cvt_pk_f32_fp8(v, true);
        a0 += lo.x; a1 += lo.y; a2 += hi.x; a3 += hi.y;
        m += maskA[j];
    }
    uint o0 = ((uint)f2bf(a1) << 16) | (uint)f2bf(a0);
    uint o1 = ((uint)f2bf(a3) << 16) | (uint)f2bf(a2);
    *(uint2*)(outb + (long)node * HD + ql * 4) = make_uint2(o0, o1);
    if (ql == 0) maskB[node] = (m > 0.f) ? 1.f : 0.f;
}

// ---------------- MFMA dense kernels ----------------
// A frag: row = l&15, k = (l>>4)*8 + j ; B frag: col = l&15 (transposed-W LDS)
// C/D: col = l&15, row = (l>>4)*4 + reg ; LDS swizzle: idx = (r*64+k) ^ ((r&7)<<3)

template <int MODE>
__global__ __launch_bounds__(256)
void gin_mfma(const float* __restrict__ agg, const ushort* __restrict__ aggb,
              const float* __restrict__ w1f, const float* __restrict__ W1,
              const float* __restrict__ b1, const float* __restrict__ W2,
              const float* __restrict__ b2, const float* __restrict__ bn1,
              const float* __restrict__ mask, const float* __restrict__ bn2p,
              ushort* __restrict__ hbout, unsigned char* __restrict__ h8, int n) {
    __shared__ ushort wt1[4096];
    __shared__ ushort wt2[4096];
    __shared__ ushort z1[4096];
    int tid = threadIdx.x;
    int l = tid & 63;
    int w = __builtin_amdgcn_readfirstlane(tid >> 6);
    int row0 = blockIdx.x * 64;
    int rbase = row0 + w * 16;
    int lrow = l & 15, lgrp = l >> 4;

#pragma unroll
    for (int i = 0; i < 16; ++i) {
        int e = i * 256 + tid;
        int k = e >> 6, c = e & 63;
        int idx = (c * 64 + k) ^ ((c & 7) << 3);
        if (MODE == 1) wt1[idx] = f2bf(W1[e]);
        wt2[idx] = f2bf(W2[e]);
    }
    __syncthreads();

    int zb = w * 1024;
    if (MODE == 0) {
        float w1v = w1f[l], b1v = b1[l];
#pragma unroll
        for (int i = 0; i < 16; ++i) {
            int grow = rbase + i; if (grow > n - 1) grow = n - 1;
            float a = agg[grow];
            float v = fmaxf(a * w1v + b1v, 0.f);
            z1[zb + ((i * 64 + l) ^ ((i & 7) << 3))] = f2bf(v);
        }
    } else {
        int arow = rbase + lrow; if (arow > n - 1) arow = n - 1;
        s16x8 a0 = *(const s16x8*)(aggb + arow * HD + lgrp * 8);
        s16x8 a1 = *(const s16x8*)(aggb + arow * HD + 32 + lgrp * 8);
#pragma unroll
        for (int ct = 0; ct < 4; ++ct) {
            int c = ct * 16 + lrow;
            s16x8 bb0 = *(const s16x8*)&wt1[(c * 64 + lgrp * 8) ^ ((c & 7) << 3)];
            s16x8 bb1 = *(const s16x8*)&wt1[(c * 64 + 32 + lgrp * 8) ^ ((c & 7) << 3)];
            f32x4 acc = {0.f, 0.f, 0.f, 0.f};
            acc = __builtin_amdgcn_mfma_f32_16x16x32_bf16(a0, bb0, acc, 0, 0, 0);
            acc = __builtin_amdgcn_mfma_f32_16x16x32_bf16(a1, bb1, acc, 0, 0, 0);
            float bv1 = b1[c];
#pragma unroll
            for (int r = 0; r < 4; ++r) {
                int rl = lgrp * 4 + r;
                float v = fmaxf(acc[r] + bv1, 0.f);
                z1[zb + ((rl * 64 + c) ^ ((rl & 7) << 3))] = f2bf(v);
            }
        }
    }
    s16x8 a0 = *(const s16x8*)&z1[zb + ((lrow * 64 + lgrp * 8) ^ ((lrow & 7) << 3))];
    s16x8 a1 = *(const s16x8*)&z1[zb + ((lrow * 64 + 32 + lgrp * 8) ^ ((lrow & 7) << 3))];

    float mk[4];
#pragma unroll
    for (int r = 0; r < 4; ++r) {
        int grow = rbase + lgrp * 4 + r; if (grow > n - 1) grow = n - 1;
        mk[r] = mask[grow];
    }

#pragma unroll
    for (int ct = 0; ct < 4; ++ct) {
        int c = ct * 16 + lrow;
        s16x8 bb0 = *(const s16x8*)&wt2[(c * 64 + lgrp * 8) ^ ((c & 7) << 3)];
        s16x8 bb1 = *(const s16x8*)&wt2[(c * 64 + 32 + lgrp * 8) ^ ((c & 7) << 3)];
        f32x4 acc = {0.f, 0.f, 0.f, 0.f};
        acc = __builtin_amdgcn_mfma_f32_16x16x32_bf16(a0, bb0, acc, 0, 0, 0);
        acc = __builtin_amdgcn_mfma_f32_16x16x32_bf16(a1, bb1, acc, 0, 0, 0);
        float g = bn1[c], be = bn1[64 + c], mn = bn1[128 + c], var = bn1[192 + c];
        float A1 = g / sqrtf(var + BN_EPS), C1 = be - mn * A1;
        float A2 = 1.f, C2 = 0.f;
        if (MODE == 1) {
            float g2 = bn2p[c], be2 = bn2p[64 + c], mn2 = bn2p[128 + c], var2 = bn2p[192 + c];
            A2 = g2 / sqrtf(var2 + BN_EPS); C2 = be2 - mn2 * A2;
        }
        float bv2 = b2[c];
#pragma unroll
        for (int r = 0; r < 4; ++r) {
            int rl = lgrp * 4 + r;
            int grow = rbase + rl;
            if (grow < n) {
                int gi = grow * HD + c;
                float v = fmaxf(acc[r] + bv2, 0.f) * A1 + C1;
                if (MODE == 1) v += bf2f(hbout[gi]);   // residual (in place)
                v *= mk[r];
                if (MODE == 1) v = v * A2 + C2;
                hbout[gi] = f2bf(v);
                h8[gi] = f2f8(v);
            }
        }
    }
}

// head: t = bn2(leaky(X@l1w+b1)*mask); hs = leaky(t@l2w+l2b)*mask
__global__ __launch_bounds__(256)
void head_mfma(const ushort* __restrict__ hb, const float* __restrict__ W1,
               const float* __restrict__ b1, const float* __restrict__ mask,
               const float* __restrict__ bn2p, const float* __restrict__ l2w,
               const float* __restrict__ l2b, float* __restrict__ hs, int n) {
    __shared__ ushort wt1[4096];
    int tid = threadIdx.x;
    int l = tid & 63;
    int w = __builtin_amdgcn_readfirstlane(tid >> 6);
    int row0 = blockIdx.x * 64;
    int rbase = row0 + w * 16;
    int lrow = l & 15, lgrp = l >> 4;

#pragma unroll
    for (int i = 0; i < 16; ++i) {
        int e = i * 256 + tid;
        int k = e >> 6, c = e & 63;
        wt1[(c * 64 + k) ^ ((c & 7) << 3)] = f2bf(W1[e]);
    }
    __syncthreads();

    int arow = rbase + lrow; if (arow > n - 1) arow = n - 1;
    s16x8 a0 = *(const s16x8*)(hb + arow * HD + lgrp * 8);
    s16x8 a1 = *(const s16x8*)(hb + arow * HD + 32 + lgrp * 8);

    float mk[4];
#pragma unroll
    for (int r = 0; r < 4; ++r) {
        int grow = rbase + lgrp * 4 + r; if (grow > n - 1) grow = n - 1;
        mk[r] = mask[grow];
    }

    float part[4] = {0.f, 0.f, 0.f, 0.f};
#pragma unroll
    for (int ct = 0; ct < 4; ++ct) {
        int c = ct * 16 + lrow;
        s16x8 bb0 = *(const s16x8*)&wt1[(c * 64 + lgrp * 8) ^ ((c & 7) << 3)];
        s16x8 bb1 = *(const s16x8*)&wt1[(c * 64 + 32 + lgrp * 8) ^ ((c & 7) << 3)];
        f32x4 acc = {0.f, 0.f, 0.f, 0.f};
        acc = __builtin_amdgcn_mfma_f32_16x16x32_bf16(a0, bb0, acc, 0, 0, 0);
        acc = __builtin_amdgcn_mfma_f32_16x16x32_bf16(a1, bb1, acc, 0, 0, 0);
        float g = bn2p[c], be = bn2p[64 + c], mn = bn2p[128 + c], var = bn2p[192 + c];
        float A2 = g / sqrtf(var + BN_EPS), C2 = be - mn * A2;
        float bv = b1[c];
        float w2v = l2w[c];
#pragma unroll
        for (int r = 0; r < 4; ++r) {
            float v = acc[r] + bv;
            v = (v > 0.f) ? v : 0.01f * v;
            v *= mk[r];
            v = v * A2 + C2;
            part[r] += v * w2v;
        }
    }
    float l2b0 = l2b[0];
#pragma unroll
    for (int r = 0; r < 4; ++r) {
        float p = part[r];
        p += __shfl_xor(p, 1, 64);
        p += __shfl_xor(p, 2, 64);
        p += __shfl_xor(p, 4, 64);
        p += __shfl_xor(p, 8, 64);
        int grow = rbase + lgrp * 4 + r;
        if (lrow == 0 && grow < n) {
            float z = p + l2b0;
            z = (z > 0.f) ? z : 0.01f * z;
            hs[grow] = z * mk[r];
        }
    }
}

// ---------------- per-graph stats ----------------

__global__ __launch_bounds__(256)
void graph_stats(const float* __restrict__ hs, const float* __restrict__ deg,
                 const int* __restrict__ gstart, const float* __restrict__ recf,
                 const float* __restrict__ totv, const float* __restrict__ trand,
                 float* __restrict__ gmax, float* __restrict__ gmin,
                 float* __restrict__ gtar) {
    __shared__ float smx[256], smn[256], ssm[256];
    int b = blockIdx.x, tid = threadIdx.x;
    int s = gstart[b], e = gstart[b + 1];
    float mx = -INFINITY, mn = INFINITY, sm = 0.f;
    for (int i = s + tid; i < e; i += 256) {
        float v = hs[i];
        mx = fmaxf(mx, v); mn = fminf(mn, v); sm += deg[i];
    }
    smx[tid] = mx; smn[tid] = mn; ssm[tid] = sm;
    __syncthreads();
    for (int o = 128; o > 0; o >>= 1) {
        if (tid < o) {
            smx[tid] = fmaxf(smx[tid], smx[tid + o]);
            smn[tid] = fminf(smn[tid], smn[tid + o]);
            ssm[tid] += ssm[tid + o];
        }
        __syncthreads();
    }
    if (tid == 0) {
        gmax[b] = smx[0];
        gmin[b] = smn[0];
        float tv = ssm[0] + 1e-6f;
        float feas = recf[b] / totv[b];
        gtar[b] = (trand[b] * feas * 0.85f + 0.1f) * tv;
    }
}

// ---------------- 30-iteration scan (with fused min-max norm) ----------------

__global__ __launch_bounds__(256)
void scan_iters(float* __restrict__ hs, const float* __restrict__ deg,
                const float* __restrict__ mask, const float* __restrict__ x,
                const int* __restrict__ gstart, const float* __restrict__ gmax,
                const float* __restrict__ gmin, const float* __restrict__ gtar,
                float* __restrict__ ga) {
    __shared__ float w1[4], w2[4];
    __shared__ float a_sh;
    int b = blockIdx.x, tid = threadIdx.x;
    int lane = tid & 63, wid = tid >> 6;
    int s = gstart[b], e = gstart[b + 1];
    float target = gtar[b];
    float gmn = gmin[b], gmx = gmax[b];
    float inv = 1.f / ((gmx + 1e-6f) - gmn);
    int cnt = e - s;
    float a = 1.f;

    if (cnt <= 2048) {
        float hv[8], dm[8], hdm[8];
        float Sdm = 0.f;
#pragma unroll
        for (int k = 0; k < 8; ++k) {
            int i = s + tid + k * 256;
            float h_ = 0.f, d_ = 0.f, m_ = 0.f;
            if (i < e) {
                float raw = hs[i]; d_ = deg[i]; m_ = mask[i];
                h_ = (raw - gmn) * inv;
                h_ = h_ * m_ + m_ * 1e-6f + x[i];
                hs[i] = h_;
            }
            hv[k] = h_;
            float t = d_ * m_;
            dm[k] = t;
            hdm[k] = h_ * t;
            Sdm += t;
        }
        {
            float v = Sdm;
#pragma unroll
            for (int o = 32; o > 0; o >>= 1) v += __shfl_down(v, o, 64);
            if (lane == 0) w1[wid] = v;
            __syncthreads();
            if (tid == 0) a_sh = w1[0] + w1[1] + w1[2] + w1[3];
            __syncthreads();
            Sdm = a_sh;
            __syncthreads();
        }
        for (int it = 0; it < 30; ++it) {
            float t1 = 0.f, t2 = 0.f;
#pragma unroll
            for (int k = 0; k < 8; ++k) {
                float keep = (a * hv[k] < 1.f) ? 1.f : 0.f;
                t1 += dm[k] * keep;
                t2 += hdm[k] * keep;
            }
#pragma unroll
            for (int o = 32; o > 0; o >>= 1) {
                t1 += __shfl_down(t1, o, 64);
                t2 += __shfl_down(t2, o, 64);
            }
            if (lane == 0) { w1[wid] = t1; w2[wid] = t2; }
            __syncthreads();
            if (tid == 0) {
                float dnk = Sdm - (w1[0] + w1[1] + w1[2] + w1[3]);
                float dot = w2[0] + w2[1] + w2[2] + w2[3];
                a_sh = (target - dnk) / (dot + 1e-5f);
            }
            __syncthreads();
            a = a_sh;
        }
    } else {
        __shared__ float s1[256], s2[256];
        for (int i = s + tid; i < e; i += 256) {
            float raw = hs[i], m_ = mask[i];
            float h_ = (raw - gmn) * inv;
            hs[i] = h_ * m_ + m_ * 1e-6f + x[i];
        }
        __syncthreads();
        for (int it = 0; it < 30; ++it) {
            float dnk = 0.f, dot = 0.f;
            for (int i = s + tid; i < e; i += 256) {
                float hv = hs[i], d = deg[i], m = mask[i];
                float keep = (a * hv < 1.f) ? 1.f : 0.f;
                float km = keep * m;
                dnk += d * (m - km);
                dot += hv * d * km;
            }
            s1[tid] = dnk; s2[tid] = dot;
            __syncthreads();
            for (int o = 128; o > 0; o >>= 1) {
                if (tid < o) { s1[tid] += s1[tid + o]; s2[tid] += s2[tid + o]; }
                __syncthreads();
            }
            if (tid == 0) a_sh = (target - s1[0]) / (s2[0] + 1e-5f);
            __syncthreads();
            a = a_sh;
        }
    }
    if (tid == 0) ga[b] = a;
}

// ---------------- probs + cut ----------------

__global__ __launch_bounds__(256)
void k_probs(const float* __restrict__ hs, const float* __restrict__ mask,
             const float* __restrict__ deg, const int* __restrict__ batch,
             const float* __restrict__ ga, float* __restrict__ out,
             float* __restrict__ cutpad, int n) {
    int i = blockIdx.x * 256 + threadIdx.x;
    bool valid = i < n;
    int b = valid ? batch[i] : 0;
    float contrib = 0.f;
    if (valid) {
        float p = ga[b] * hs[i] * mask[i];
        p = fminf(fmaxf(p, 0.f), 1.f);
        out[i] = p;
        contrib = p * deg[i];
    }
    int b0 = __shfl(b, 0, 64);
    bool uni = __all(b == b0);
    if (uni) {
#pragma unroll
        for (int o = 32; o > 0; o >>= 1) contrib += __shfl_down(contrib, o, 64);
        if ((threadIdx.x & 63) == 0) atomicAdd(&cutpad[b0 * 16], contrib);
    } else if (valid) {
        atomicAdd(&cutpad[b * 16], contrib);
    }
}

__global__ __launch_bounds__(256)
void cut_edges(const int* __restrict__ row, const int* __restrict__ col,
               const int* __restrict__ batch, const float* __restrict__ probs,
               float* __restrict__ cutpad, int E) {
    __shared__ float lc[128];
    int tid = threadIdx.x;
    if (tid < 128) lc[tid] = 0.f;
    __syncthreads();
    for (int e = blockIdx.x * 256 + tid; e < E; e += gridDim.x * 256) {
        int r = row[e], c = col[e];
        float v = probs[r] * probs[c];
        atomicAdd(&lc[batch[r]], v);
    }
    __syncthreads();
    if (tid < 128) {
        float v = lc[tid];
        if (v != 0.f) atomicAdd(&cutpad[tid * 16], -v);
    }
}

__global__ void k_loss(const float* __restrict__ cutpad, float* __restrict__ out, int nidx, int B) {
    __shared__ float sd[128];
    int tid = threadIdx.x;
    sd[tid] = (tid < B) ? cutpad[tid * 16] : 0.f;
    __syncthreads();
    for (int o = 64; o > 0; o >>= 1) {
        if (tid < o) sd[tid] += sd[tid + o];
        __syncthreads();
    }
    if (tid == 0) out[nidx] = sd[0] / (float)B;
}

// ---------------- host ----------------

extern "C" void kernel_launch(void* const* d_in, const int* in_sizes, int n_in,
                              void* d_out, int out_size, void* d_ws, size_t ws_size,
                              hipStream_t stream) {
    const float* x     = (const float*)d_in[0];
    const int*   ei    = (const int*)d_in[1];
    const int*   batch = (const int*)d_in[2];
    const float* recf  = (const float*)d_in[3];
    const float* totv  = (const float*)d_in[4];
    const float* trand = (const float*)d_in[5];
    const float* c1w1  = (const float*)d_in[6];
    const float* c1b1  = (const float*)d_in[7];
    const float* c1w2  = (const float*)d_in[8];
    const float* c1b2  = (const float*)d_in[9];
    const float* c1bn  = (const float*)d_in[10];
    const float* cw1   = (const float*)d_in[11];
    const float* cb1   = (const float*)d_in[12];
    const float* cw2   = (const float*)d_in[13];
    const float* cb2   = (const float*)d_in[14];
    const float* cbn   = (const float*)d_in[15];
    const float* obn   = (const float*)d_in[16];
    const float* l1w   = (const float*)d_in[17];
    const float* l1b   = (const float*)d_in[18];
    const float* bn2   = (const float*)d_in[19];
    const float* l2w   = (const float*)d_in[20];
    const float* l2b   = (const float*)d_in[21];

    int N  = in_sizes[0];
    int E  = in_sizes[1] / 2;
    int B  = in_sizes[3];
    int NL = in_sizes[11] / (HD * HD);
    const int* row = ei;
    const int* col = ei + E;
    int NB = (N + BSZ - 1) >> BSH;

    long NH = (long)N * HD;
    ushort* hb   = (ushort*)d_ws;            // bf16 [N][64]
    ushort* aggb = hb + NH;                  // bf16 [N][64]
    unsigned char* h8 = (unsigned char*)(aggb + NH);  // fp8 [N][64]
    float* maskA = (float*)(h8 + NH);
    float* maskB = maskA + N;
    float* deg   = maskB + N;
    float* hs    = deg + N;
    float* cutpad = hs + N;
    float* gmax  = cutpad + 2048;
    float* gmin  = gmax + B;
    float* gtar  = gmin + B;
    float* ga    = gtar + B;
    uintptr_t ip = (uintptr_t)(ga + B);
    ip = (ip + 63) & ~(uintptr_t)63;
    int* rowptr  = (int*)ip;
    int* gstart  = rowptr + N + 1;
    int* bc_col  = gstart + (B + 2);
    int* bc_row  = bc_col + 512;
    int* cbase   = bc_row + 512;
    int* rbase   = cbase + 513;
    int* cur_col = rbase + 513;              // padded x16
    int* cur_row = cur_col + 512 * 16;       // padded x16
    int* srcs    = cur_row + 512 * 16;
    uint* ebuf    = (uint*)hb;    // alias: dead once gin_mfma<0> writes hb
    ushort* rbuf  = aggb;         // alias: dead once gather writes aggb

    dim3 blk(256);
    int gN  = (N + 255) / 256;
    int gMM = (N + 63) / 64;
    int g16 = (N + 15) / 16;
    int gP  = (E + PCH2 - 1) / PCH2;
    int gH  = min((E + 255) / 256, 1024);

    // ---- preprocessing ----
    k_gstart_pre<<<1, blk, 0, stream>>>(gstart, N, B);
    k_init<<<gN, blk, 0, stream>>>(cutpad, gstart, bc_col, bc_row, batch, N, B);
    k_hist<<<gH, blk, 0, stream>>>(row, col, bc_col, bc_row, E);
    scan_mid<<<1, blk, 0, stream>>>(bc_col, bc_row, cbase, rbase, cur_col, cur_row,
                                    gstart, rowptr, N, B, NB, E);
    k_partition<<<gP, blk, 0, stream>>>(row, col, ebuf, rbuf, cur_col, cur_row, E);
    k_bucket_all<<<NB, blk, 0, stream>>>(ebuf, cbase, rbuf, rbase, x, rowptr,
                                         maskA, srcs, deg, N);

    // ---- layer 0 ----
    k_gather_s<<<gN, blk, 0, stream>>>(x, rowptr, srcs, hs, N);
    gin_mfma<0><<<gMM, blk, 0, stream>>>(hs, nullptr, c1w1, nullptr, c1b1,
                                         c1w2, c1b2, c1bn, maskA, nullptr, hb, h8, N);

    // ---- GIN loop ----
    for (int i = 0; i < NL; ++i) {
        gather_f8<<<g16, blk, 0, stream>>>(h8, hb, rowptr, srcs, maskA, aggb, maskB, N);
        gin_mfma<1><<<gMM, blk, 0, stream>>>(nullptr, aggb, nullptr, cw1 + i * 4096,
                                             cb1 + i * 64, cw2 + i * 4096, cb2 + i * 64,
                                             cbn + i * 256, maskB, obn + i * 256, hb, h8, N);
        float* t = maskA; maskA = maskB; maskB = t;
    }

    // ---- head + tail ----
    head_mfma<<<gMM, blk, 0, stream>>>(hb, l1w, l1b, maskA, bn2, l2w, l2b, hs, N);
    graph_stats<<<B, blk, 0, stream>>>(hs, deg, gstart, recf, totv, trand, gmax, gmin, gtar);
    scan_iters<<<B, blk, 0, stream>>>(hs, deg, maskA, x, gstart, gmax, gmin, gtar, ga);
    k_probs<<<gN, blk, 0, stream>>>(hs, maskA, deg, batch, ga, (float*)d_out, cutpad, N);
    cut_edges<<<512, blk, 0, stream>>>(row, col, batch, (float*)d_out, cutpad, E);
    k_loss<<<1, 128, 0, stream>>>(cutpad, (float*)d_out, N, B);
}